// Round 36
// baseline (66.915 us; speedup 1.0000x reference)
//
#include <hip/hip_runtime.h>
#include <cmath>
#include <stdint.h>

#pragma clang fp contract(off)

// Register barrier: isolates each FP op (no contraction/reassociation).
__device__ __forceinline__ void opqf(float& v) { asm volatile("" : "+v"(v)); }

__device__ __forceinline__ uint32_t fbits(float f) { return __float_as_uint(f); }
__device__ __forceinline__ float bitsf(uint32_t u) { return __uint_as_float(u); }

// combos = sorted(itertools.combinations(range(8), 2))
__device__ __constant__ int d_CI[28] = {0,0,0,0,0,0,0,1,1,1,1,1,1,2,2,2,2,2,3,3,3,3,4,4,4,5,5,6};
__device__ __constant__ int d_CJ[28] = {1,2,3,4,5,6,7,2,3,4,5,6,7,3,4,5,6,7,4,5,6,7,5,6,7,6,7,7};

// 210 disjoint pairs in PAIRS lexicographic order, packed (a*4)<<16 | (b*4).
// GENERATED at compile time (exactly mirrors the reference's PAIRS build) —
// no hand-counting errors possible.
struct PairTab { uint32_t v[210]; };
constexpr PairTab make_pairs() {
    PairTab t{};
    int CI_[28] = {0,0,0,0,0,0,0,1,1,1,1,1,1,2,2,2,2,2,3,3,3,3,4,4,4,5,5,6};
    int CJ_[28] = {1,2,3,4,5,6,7,2,3,4,5,6,7,3,4,5,6,7,4,5,6,7,5,6,7,6,7,7};
    int k = 0;
    for (int a = 0; a < 28; ++a) {
        for (int b = a + 1; b < 28; ++b) {
            unsigned ma = (1u << CI_[a]) | (1u << CJ_[a]);
            unsigned mb = (1u << CI_[b]) | (1u << CJ_[b]);
            if (ma & mb) continue;
            t.v[k++] = (uint32_t)(((a * 4) << 16) | (b * 4));
        }
    }
    return t;
}
__device__ __constant__ PairTab d_PAIR = make_pairs();

__global__ __launch_bounds__(256) void mass_asym_kernel(const float* __restrict__ x,
                                                        float* __restrict__ out,
                                                        int n) {
#pragma clang fp contract(off)
    __shared__ float sm[256 * 29];                      // stride 29: 2-lane/bank (free)
    int t = blockIdx.x * blockDim.x + threadIdx.x;
    if (t >= n) return;

    constexpr int CI[28] = {0,0,0,0,0,0,0,1,1,1,1,1,1,2,2,2,2,2,3,3,3,3,4,4,4,5,5,6};
    constexpr int CJ[28] = {1,2,3,4,5,6,7,2,3,4,5,6,7,3,4,5,6,7,4,5,6,7,5,6,7,6,7,7};

    const float4* xp = reinterpret_cast<const float4*>(x) + (size_t)t * 8;
    float E[8], px[8], py[8], pz[8];
#pragma unroll
    for (int i = 0; i < 8; ++i) {
        float4 v = xp[i];
        E[i] = v.x; px[i] = v.y; py[i] = v.z; pz[i] = v.w;
    }

    float* myrow = &sm[threadIdx.x * 29];

    // PROVEN REFERENCE PIPELINE (R32-R34, passes absmax 4.5):
    //   acc0 = a*a; acc1 = b*b; acc0 = fma(d,d,acc0); s = acc0+acc1
    //   e2 = e*e; m2 = e2 - s;  m = HW CR f32 sqrt
#pragma unroll
    for (int c = 0; c < 28; ++c) {
        float e = E[CI[c]]  + E[CJ[c]];  opqf(e);
        float a = px[CI[c]] + px[CJ[c]]; opqf(a);
        float b = py[CI[c]] + py[CJ[c]]; opqf(b);
        float d = pz[CI[c]] + pz[CJ[c]]; opqf(d);
        float acc0 = a * a; opqf(acc0);
        float acc1 = b * b; opqf(acc1);
        acc0 = __builtin_fmaf(d, d, acc0); opqf(acc0);
        float s = acc0 + acc1; opqf(s);
        float e2 = e * e; opqf(e2);
        float m2 = e2 - s; opqf(m2);
        myrow[c] = sqrtf(m2);                       // HW CR f32 sqrt
    }

    // COMPACT pair loop (tiny code, I-cache friendly). Same IEEE op sequence
    // as R34 (sub, |.|, add, CR divide, uint compare, first-min) -> selection
    // bit-identical. Table is lane-uniform -> scalar loads.
    const uint32_t base = (uint32_t)(threadIdx.x * 29 * 4);
    uint32_t ubest = 0x7f800000u;   // +inf
    uint32_t bpent = d_PAIR.v[0];   // winner's packed entry
#pragma unroll 8
    for (int p = 0; p < 210; ++p) {
        uint32_t e = d_PAIR.v[p];                   // uniform -> SGPR
        float va = *(const float*)((const char*)sm + (base + (e >> 16)));
        float vb = *(const float*)((const char*)sm + (base + (e & 0xffffu)));
        float num = fabsf(va - vb);                 // exact IEEE sub+abs
        float den = va + vb;                        // exact IEEE add
        float v = num / den;                        // HW CR f32 divide
        uint32_t uv = fbits(v);
        bool better = uv < ubest;
        ubest = better ? uv : ubest;
        bpent = better ? e : bpent;
    }

    const int ba = (int)(bpent >> 18);              // (a*4)<<16 -> a
    const int bb = (int)((bpent & 0xffffu) >> 2);   // b*4 -> b

    float bma = myrow[ba];
    float bmb = myrow[bb];

    float* o = out + (size_t)t * 7;
    o[0] = (float)d_CI[ba];
    o[1] = (float)d_CJ[ba];
    o[2] = (float)d_CI[bb];
    o[3] = (float)d_CJ[bb];
    o[4] = bma;
    o[5] = bmb;
    o[6] = bitsf(ubest);
}

extern "C" void kernel_launch(void* const* d_in, const int* in_sizes, int n_in,
                              void* d_out, int out_size, void* d_ws, size_t ws_size,
                              hipStream_t stream) {
    const float* x = (const float*)d_in[0];
    float* out = (float*)d_out;
    const int n = in_sizes[0] / 32;          // events
    const int block = 256;
    const int grid = (n + block - 1) / block;
    mass_asym_kernel<<<grid, block, 0, stream>>>(x, out, n);
}